// Round 7
// baseline (73.404 us; speedup 1.0000x reference)
//
#include <hip/hip_runtime.h>

// Hamiltonian flow, separable H: dq/dt = p ; dp/dt = -(q + q^3), m(q)=q+q^3.
// R1 72us scalar -> R3 ~36us packed (v_pk_fma_f32) -> R5/R6 ~34us (18 pk
// ops/step). R6 neutrality => no longer instr-count-bound; effective ~9
// cyc/instr at 2 waves/SIMD. R7 discriminator: 4 pairs/thread = TWO
// independent packed chains per thread, 65536 threads -> 1024 waves ->
// 1 wave/SIMD. Same total instrs, 2x per-wave ILP, half the waves.
//   cadence-capped -> ~2x worse ; latency/ILP-bound -> ~1.5x better ;
//   clock-throttled -> unchanged.

typedef float v2f __attribute__((ext_vector_type(2)));

__device__ __forceinline__ v2f vfma(v2f a, v2f b, v2f c) {
    return __builtin_elementwise_fma(a, b, c);
}

struct RkConsts {
    v2f dt, h, nc1, nc2, nc3, ndt6, two;
};

__device__ __forceinline__ void rk4_step(v2f& q, v2f& p, const RkConsts& C) {
    v2f u1 = q * q;
    v2f m1 = vfma(u1, q, q);        // m(q)
    v2f qa = vfma(C.h,  p, q);      // q + h p
    v2f q2 = vfma(C.dt, p, q);      // q + dt p

    v2f u2 = qa * qa;
    v2f m2 = vfma(u2, qa, qa);      // m(qa)
    v2f qb = vfma(C.nc1, m1, qa);   // qa - (dt^2/4) m1

    v2f u3 = qb * qb;
    v2f m3 = vfma(u3, qb, qb);      // m(qb)
    v2f qc = vfma(C.nc2, m2, q2);   // q2 - (dt^2/2) m2

    v2f u4 = qc * qc;
    v2f m4 = vfma(u4, qc, qc);      // m(qc)

    v2f a1 = m1 + m4;
    v2f a2 = m2 + m3;

    v2f s3 = vfma(C.two, a2, a1);   // a1 + 2 a2
    p = vfma(C.ndt6, s3, p);        // p - dt/6 (...)

    v2f t2 = m1 + a2;
    q = vfma(C.nc3, t2, q2);        // q2 - dt^2/6 (...)
}

__global__ __launch_bounds__(256) void HamiltonianFlow_23957327577411_kernel(
    const float4* __restrict__ x0, float4* __restrict__ out, int n4, int half)
{
    int i = blockIdx.x * blockDim.x + threadIdx.x;
    if (i >= half) return;

    float4 vA = x0[i];
    float4 vB = x0[i + half];

    v2f qA = {vA.x, vA.z}, pA = {vA.y, vA.w};
    v2f qB = {vB.x, vB.z}, pB = {vB.y, vB.w};

    const float dt_s = (float)(10.0 / 255.0);
    const float h_s  = 0.5f * dt_s;

    RkConsts C;
    C.dt   = (v2f){dt_s, dt_s};
    C.h    = (v2f){h_s, h_s};
    C.nc1  = (v2f){-dt_s * dt_s * 0.25f,       -dt_s * dt_s * 0.25f};
    C.nc2  = (v2f){-dt_s * dt_s * 0.5f,        -dt_s * dt_s * 0.5f};
    C.nc3  = (v2f){-dt_s * dt_s * (1.0f/6.0f), -dt_s * dt_s * (1.0f/6.0f)};
    C.ndt6 = (v2f){-dt_s * (1.0f/6.0f),        -dt_s * (1.0f/6.0f)};
    C.two  = (v2f){2.0f, 2.0f};

    #pragma unroll 5
    for (int s = 0; s < 255; ++s) {
        // two fully independent packed chains -> 2x per-wave ILP
        rk4_step(qA, pA, C);
        rk4_step(qB, pB, C);
    }

    out[i]        = make_float4(qA.x, pA.x, qA.y, pA.y);
    out[i + half] = make_float4(qB.x, pB.x, qB.y, pB.y);
}

extern "C" void kernel_launch(void* const* d_in, const int* in_sizes, int n_in,
                              void* d_out, int out_size, void* d_ws, size_t ws_size,
                              hipStream_t stream) {
    const float4* x0 = (const float4*)d_in[0];
    float4* out = (float4*)d_out;
    int n4 = in_sizes[0] / 4;       // total float4s (2 pairs each) = 131072
    int half = n4 / 2;              // threads: 65536 -> 256 blocks x 256
    int block = 256;
    int grid = (half + block - 1) / block;
    HamiltonianFlow_23957327577411_kernel<<<grid, block, 0, stream>>>(x0, out, n4, half);
}